// Round 5
// baseline (121.747 us; speedup 1.0000x reference)
//
#include <hip/hip_runtime.h>
#include <cmath>

#define B_ 2
#define X_ 128
#define Y_ 128
#define Z_ 128
#define C_ 8
#define ZC 1024         // Z_*C_
#define ZC4 256         // ZC/4
#define XS 131072       // Y_*ZC, stride of x in elements
#define BS 16777216     // X_*XS, stride of batch in elements
#define PF4 32768       // float4s per (b,x) plane = XS/4
#define KTAPS 13
#define TAIL 6

struct Taps { float k[KTAPS]; };

__device__ __forceinline__ float4 ld4(const float* p) {
    return *reinterpret_cast<const float4*>(p);
}
__device__ __forceinline__ void st4(float* p, const float4& v) {
    *reinterpret_cast<float4*>(p) = v;
}
__device__ __forceinline__ float4 f4zero() { return make_float4(0.f, 0.f, 0.f, 0.f); }
__device__ __forceinline__ void fma4(float4& a, float s, const float4& b) {
    a.x = fmaf(s, b.x, a.x); a.y = fmaf(s, b.y, a.y);
    a.z = fmaf(s, b.z, a.z); a.w = fmaf(s, b.w, a.w);
}

// ---------------- Pass A: conv along X, stateless gather ---------------------
// Round-4 post-mortem: compiler's default occupancy target capped VGPR at 64,
// which cannot hold the 28-float4 burst (112 regs) -> loads were re-sunk into
// the FMA stream, effective MLP ~7-13, latency-bound at 2.87 TB/s.
// Fix: __launch_bounds__(256,1) lifts the VGPR cap; the asm memory fence
// forbids sinking loads past it -> all 28 independent 1KB wave-loads issued
// back-to-back (true MLP=28). Boundary predicates are block-uniform.
template <int W>
__global__ __launch_bounds__(256, 1) void xconv_gather(const float* __restrict__ src,
                                                       float* __restrict__ dst,
                                                       Taps tp) {
    const int gid = blockIdx.x;
    const int fc  = gid & (PF4 / 256 - 1);          // 128 f-chunks (inner: cohort
    const int xw  = (gid >> 7) & (X_ / W - 1);      //  of 128 blocks covers full
    const int b   = gid >> 10;                      //  planes densely)

    const int f4   = fc * 256 + threadIdx.x;        // float4 index in plane
    const int x0   = xw * W;
    const int base = b * BS + (f4 << 2);

    float4 v[W + 2 * TAIL];
#pragma unroll
    for (int i = 0; i < W + 2 * TAIL; ++i) {
        const int xx = x0 - TAIL + i;
        v[i] = (xx >= 0 && xx < X_) ? ld4(src + base + xx * XS) : f4zero();
    }
    // Do not let the compiler sink loads into the compute loop.
    asm volatile("" ::: "memory");

#pragma unroll
    for (int j = 0; j < W; ++j) {
        float4 acc = f4zero();
#pragma unroll
        for (int i = 0; i < KTAPS; ++i) fma4(acc, tp.k[i], v[j + i]);
        st4(dst + base + (x0 + j) * XS, acc);
    }
}

// ------------- Pass B: fused conv along Y (registers) + Z (LDS row) ----------
// Block = 256 threads covering one full (z,c) row (1024 floats as float4s) of
// one (b,x) plane; slides along a Y segment. Y-result row -> LDS
// (double-buffered); Z-conv reads 13 z-neighbors from that LDS row and writes
// the final output. Loads march contiguously (+4KB/iter) -> DRAM-friendly,
// measured ~5.2 TB/s.
template <int SEGY>
__global__ __launch_bounds__(256) void yzconv_kernel(const float* __restrict__ src,
                                                     float* __restrict__ dst,
                                                     Taps tp) {
    __shared__ float row[2][ZC];

    const int t  = threadIdx.x;           // 0..255
    const int x  = blockIdx.x & (X_ - 1);
    int rest     = blockIdx.x >> 7;
    const int b  = rest & (B_ - 1);
    const int s  = rest >> 1;

    const int pbase = b * BS + x * XS;    // plane base
    const int zc    = t << 2;             // word offset in row, float4-aligned
    const int z     = t >> 1;
    const int cw    = (t & 1) << 2;

    const int ylen = Y_ / SEGY;
    const int y0   = s * ylen;

    float4 w[KTAPS];
#pragma unroll
    for (int i = 0; i < KTAPS - 1; ++i) {
        const int yy = y0 - TAIL + i;
        w[i] = (yy >= 0 && yy < Y_) ? ld4(src + pbase + yy * ZC + zc) : f4zero();
    }
    const int yl = y0 + TAIL;
    float4 nv = (yl < Y_) ? ld4(src + pbase + yl * ZC + zc) : f4zero();

    int p = 0;
    for (int y = y0; y < y0 + ylen; ++y) {
        const int yf = y + TAIL + 1;
        float4 fut = (yf < Y_) ? ld4(src + pbase + yf * ZC + zc) : f4zero();

        // Y conv
        w[KTAPS - 1] = nv;
        float4 acc = f4zero();
#pragma unroll
        for (int i = 0; i < KTAPS; ++i) fma4(acc, tp.k[i], w[i]);
        st4(&row[p][zc], acc);
        __syncthreads();

        // Z conv from LDS (offsets are 4t + 8*(i-6): linear in lane, conflict-free)
        float4 zacc = f4zero();
#pragma unroll
        for (int i = 0; i < KTAPS; ++i) {
            const int zz = z - TAIL + i;
            if (zz >= 0 && zz < Z_) {
                float4 vv = ld4(&row[p][(zz << 3) + cw]);
                fma4(zacc, tp.k[i], vv);
            }
        }
        st4(dst + pbase + y * ZC + zc, zacc);

#pragma unroll
        for (int i = 0; i < KTAPS - 1; ++i) w[i] = w[i + 1];
        nv = fut;
        p ^= 1;
        // single barrier per iter is safe: next write goes to the other buffer,
        // and the write 2 iters later is dominated by the next barrier.
    }
}

extern "C" void kernel_launch(void* const* d_in, const int* in_sizes, int n_in,
                              void* d_out, int out_size, void* d_ws, size_t ws_size,
                              hipStream_t stream) {
    const float* in = (const float*)d_in[0];
    float* out = (float*)d_out;

    // Gaussian taps: tail = int(2.0*3.0 + 0.5) = 6, K = 13, sigma = 2
    Taps tp;
    {
        float kv[KTAPS];
        float sum = 0.f;
        for (int i = 0; i < KTAPS; ++i) {
            const float xx = (float)(i - TAIL);
            kv[i] = expf(-0.5f * xx * xx / 4.0f);
            sum += kv[i];
        }
        for (int i = 0; i < KTAPS; ++i) tp.k[i] = kv[i] / sum;
    }

    const size_t need_bytes = (size_t)B_ * BS * sizeof(float);  // 134 MB
    const bool use_ws = (ws_size >= need_bytes) && (d_ws != nullptr);
    float* tmp = use_ws ? (float*)d_ws : out;

    // Pass A: X conv, gather form. Grid = B * (X/16) * (PF4/256) = 2048 blocks.
    xconv_gather<16><<<B_ * (X_ / 16) * (PF4 / 256), 256, 0, stream>>>(in, tmp, tp);

    // Pass B: fused Y+Z conv. SEGY=8 -> 2048 blocks = 32 waves/CU capacity.
    if (use_ws) {
        yzconv_kernel<8><<<B_ * X_ * 8, 256, 0, stream>>>(tmp, out, tp);
    } else {
        // in-place on d_out: safe, writes trail reads by >= 6 rows
        yzconv_kernel<1><<<B_ * X_, 256, 0, stream>>>(out, out, tp);
    }
}

// Round 6
// 120.727 us; speedup vs baseline: 1.0084x; 1.0084x over previous
//
#include <hip/hip_runtime.h>
#include <cmath>

#define B_ 2
#define X_ 128
#define Y_ 128
#define Z_ 128
#define C_ 8
#define ZC 1024         // Z_*C_
#define ZC4 256         // ZC/4
#define XS 131072       // Y_*ZC, stride of x in elements
#define BS 16777216     // X_*XS, stride of batch in elements
#define PF4 32768       // float4s per (b,x) plane = XS/4
#define KTAPS 13
#define TAIL 6

struct Taps { float k[KTAPS]; };

__device__ __forceinline__ float4 ld4(const float* p) {
    return *reinterpret_cast<const float4*>(p);
}
__device__ __forceinline__ void st4(float* p, const float4& v) {
    *reinterpret_cast<float4*>(p) = v;
}
__device__ __forceinline__ float4 f4zero() { return make_float4(0.f, 0.f, 0.f, 0.f); }
__device__ __forceinline__ void fma4(float4& a, float s, const float4& b) {
    a.x = fmaf(s, b.x, a.x); a.y = fmaf(s, b.y, a.y);
    a.z = fmaf(s, b.z, a.z); a.w = fmaf(s, b.w, a.w);
}

// ---------------- Pass A: conv along X, stateless gather ---------------------
// Round-5 post-mortem: the asm "memory" fence did NOT force the burst --
// register-only FMAs were hoisted past it (guide rule #18), VGPR stayed 64,
// effective MLP ~13. This version pins every loaded component live via
// per-value asm operand ties (each load must precede its pin) and then drops
// a sched_barrier(0) full scheduling fence: no FMA can be hoisted above it,
// so all W+12=28 independent 1KB wave-loads are in flight simultaneously
// (true MLP=28, ~112 live VGPRs).
template <int W>
__global__ __launch_bounds__(256, 1) void xconv_gather(const float* __restrict__ src,
                                                       float* __restrict__ dst,
                                                       Taps tp) {
    const int gid = blockIdx.x;
    const int fc  = gid & (PF4 / 256 - 1);          // 128 f-chunks (inner: cohort
    const int xw  = (gid >> 7) & (X_ / W - 1);      //  of 128 blocks covers full
    const int b   = gid >> 10;                      //  planes densely)

    const int f4   = fc * 256 + threadIdx.x;        // float4 index in plane
    const int x0   = xw * W;
    const int base = b * BS + (f4 << 2);

    float4 v[W + 2 * TAIL];
#pragma unroll
    for (int i = 0; i < W + 2 * TAIL; ++i) {
        const int xx = x0 - TAIL + i;
        v[i] = (xx >= 0 && xx < X_) ? ld4(src + base + xx * XS) : f4zero();
    }
    // Pin every component live here: the load feeding each pin must precede it,
    // so all 28 float4 are simultaneously resident (forces ~112 VGPRs).
#pragma unroll
    for (int i = 0; i < W + 2 * TAIL; ++i) {
        asm volatile("" : "+v"(v[i].x), "+v"(v[i].y), "+v"(v[i].z), "+v"(v[i].w));
    }
    // Full scheduler fence: nothing (incl. register-only FMAs) crosses this.
    __builtin_amdgcn_sched_barrier(0);

#pragma unroll
    for (int j = 0; j < W; ++j) {
        float4 acc = f4zero();
#pragma unroll
        for (int i = 0; i < KTAPS; ++i) fma4(acc, tp.k[i], v[j + i]);
        st4(dst + base + (x0 + j) * XS, acc);
    }
}

// ------------- Pass B: fused conv along Y (registers) + Z (LDS row) ----------
// Block = 256 threads covering one full (z,c) row (1024 floats as float4s) of
// one (b,x) plane; slides along a Y segment. Y-result row -> LDS
// (double-buffered); Z-conv reads 13 z-neighbors from that LDS row and writes
// the final output. Loads march contiguously (+4KB/iter) -> ~5.2 TB/s.
template <int SEGY>
__global__ __launch_bounds__(256) void yzconv_kernel(const float* __restrict__ src,
                                                     float* __restrict__ dst,
                                                     Taps tp) {
    __shared__ float row[2][ZC];

    const int t  = threadIdx.x;           // 0..255
    const int x  = blockIdx.x & (X_ - 1);
    int rest     = blockIdx.x >> 7;
    const int b  = rest & (B_ - 1);
    const int s  = rest >> 1;

    const int pbase = b * BS + x * XS;    // plane base
    const int zc    = t << 2;             // word offset in row, float4-aligned
    const int z     = t >> 1;
    const int cw    = (t & 1) << 2;

    const int ylen = Y_ / SEGY;
    const int y0   = s * ylen;

    float4 w[KTAPS];
#pragma unroll
    for (int i = 0; i < KTAPS - 1; ++i) {
        const int yy = y0 - TAIL + i;
        w[i] = (yy >= 0 && yy < Y_) ? ld4(src + pbase + yy * ZC + zc) : f4zero();
    }
    const int yl = y0 + TAIL;
    float4 nv = (yl < Y_) ? ld4(src + pbase + yl * ZC + zc) : f4zero();

    int p = 0;
    for (int y = y0; y < y0 + ylen; ++y) {
        const int yf = y + TAIL + 1;
        float4 fut = (yf < Y_) ? ld4(src + pbase + yf * ZC + zc) : f4zero();

        // Y conv
        w[KTAPS - 1] = nv;
        float4 acc = f4zero();
#pragma unroll
        for (int i = 0; i < KTAPS; ++i) fma4(acc, tp.k[i], w[i]);
        st4(&row[p][zc], acc);
        __syncthreads();

        // Z conv from LDS (offsets are 4t + 8*(i-6): linear in lane, conflict-free)
        float4 zacc = f4zero();
#pragma unroll
        for (int i = 0; i < KTAPS; ++i) {
            const int zz = z - TAIL + i;
            if (zz >= 0 && zz < Z_) {
                float4 vv = ld4(&row[p][(zz << 3) + cw]);
                fma4(zacc, tp.k[i], vv);
            }
        }
        st4(dst + pbase + y * ZC + zc, zacc);

#pragma unroll
        for (int i = 0; i < KTAPS - 1; ++i) w[i] = w[i + 1];
        nv = fut;
        p ^= 1;
        // single barrier per iter is safe: next write goes to the other buffer,
        // and the write 2 iters later is dominated by the next barrier.
    }
}

extern "C" void kernel_launch(void* const* d_in, const int* in_sizes, int n_in,
                              void* d_out, int out_size, void* d_ws, size_t ws_size,
                              hipStream_t stream) {
    const float* in = (const float*)d_in[0];
    float* out = (float*)d_out;

    // Gaussian taps: tail = int(2.0*3.0 + 0.5) = 6, K = 13, sigma = 2
    Taps tp;
    {
        float kv[KTAPS];
        float sum = 0.f;
        for (int i = 0; i < KTAPS; ++i) {
            const float xx = (float)(i - TAIL);
            kv[i] = expf(-0.5f * xx * xx / 4.0f);
            sum += kv[i];
        }
        for (int i = 0; i < KTAPS; ++i) tp.k[i] = kv[i] / sum;
    }

    const size_t need_bytes = (size_t)B_ * BS * sizeof(float);  // 134 MB
    const bool use_ws = (ws_size >= need_bytes) && (d_ws != nullptr);
    float* tmp = use_ws ? (float*)d_ws : out;

    // Pass A: X conv, gather form. Grid = B * (X/16) * (PF4/256) = 2048 blocks.
    xconv_gather<16><<<B_ * (X_ / 16) * (PF4 / 256), 256, 0, stream>>>(in, tmp, tp);

    // Pass B: fused Y+Z conv. SEGY=8 -> 2048 blocks = 32 waves/CU capacity.
    if (use_ws) {
        yzconv_kernel<8><<<B_ * X_ * 8, 256, 0, stream>>>(tmp, out, tp);
    } else {
        // in-place on d_out: safe, writes trail reads by >= 6 rows
        yzconv_kernel<1><<<B_ * X_, 256, 0, stream>>>(out, out, tp);
    }
}